// Round 1
// baseline (823.443 us; speedup 1.0000x reference)
//
#include <hip/hip_runtime.h>
#include <hip/hip_bf16.h>
#include <stdint.h>

#define D 256

typedef short short8 __attribute__((ext_vector_type(8)));
typedef float f32x4 __attribute__((ext_vector_type(4)));

__device__ __forceinline__ float bf2f(unsigned short u) {
  return __uint_as_float(((unsigned)u) << 16);
}
__device__ __forceinline__ unsigned short f2bf(float f) {
  unsigned u = __float_as_uint(f);
  unsigned r = u + 0x7FFFu + ((u >> 16) & 1u);
  return (unsigned short)(r >> 16);
}

// ---------------- degree histogram ----------------
__global__ void hist_kernel(const int* __restrict__ src, int* __restrict__ ecount, int E) {
  int e = blockIdx.x * 256 + threadIdx.x;
  if (e < E) atomicAdd(&ecount[src[e]], 1);
}

// ---------------- exclusive scan (3-kernel) ----------------
__global__ void scan1_kernel(const int* __restrict__ ecount, int* __restrict__ offsets,
                             int* __restrict__ sums, int n) {
  __shared__ int s[1024];
  int tid = threadIdx.x;
  int gid = blockIdx.x * 1024 + tid;
  int v = (gid < n) ? ecount[gid] : 0;
  s[tid] = v;
  __syncthreads();
  for (int off = 1; off < 1024; off <<= 1) {
    int t = (tid >= off) ? s[tid - off] : 0;
    __syncthreads();
    s[tid] += t;
    __syncthreads();
  }
  if (gid < n) offsets[gid] = s[tid] - v;   // exclusive
  if (tid == 1023) sums[blockIdx.x] = s[1023];
}

__global__ void scan2_kernel(int* __restrict__ sums, int nb) {
  __shared__ int s[128];
  int tid = threadIdx.x;
  int v = (tid < nb) ? sums[tid] : 0;
  s[tid] = v;
  __syncthreads();
  for (int off = 1; off < 128; off <<= 1) {
    int t = (tid >= off) ? s[tid - off] : 0;
    __syncthreads();
    s[tid] += t;
    __syncthreads();
  }
  if (tid < nb) sums[tid] = s[tid] - v;     // exclusive
}

__global__ void scan3_kernel(int* __restrict__ offsets, const int* __restrict__ sums,
                             int* __restrict__ cursor, const int* __restrict__ ecount,
                             float* __restrict__ rnorm, int n) {
  int gid = blockIdx.x * 1024 + threadIdx.x;
  if (gid < n) {
    int o = offsets[gid] + sums[blockIdx.x];
    offsets[gid] = o;
    cursor[gid] = o;
    rnorm[gid] = rsqrtf((float)(ecount[gid] + 1));  // +1 = self loop
  }
}

// ---------------- CSR scatter ----------------
__global__ void scatter_kernel(const int* __restrict__ src, const int* __restrict__ dst,
                               int* __restrict__ cursor, int* __restrict__ csr, int E) {
  int e = blockIdx.x * 256 + threadIdx.x;
  if (e < E) {
    int s = src[e];
    int p = atomicAdd(&cursor[s], 1);
    csr[p] = dst[e];
  }
}

// ---------------- fp32 -> bf16 conversions ----------------
__global__ void convx_kernel(const float* __restrict__ x, unsigned short* __restrict__ xb,
                             int n, int npad) {
  int i4 = blockIdx.x * 256 + threadIdx.x;
  long long elem = (long long)i4 * 4;
  if (elem >= (long long)npad * D) return;
  int row = (int)(elem / D);
  ushort4 o;
  if (row < n) {
    const float4 v = *(const float4*)&x[elem];
    o.x = f2bf(v.x); o.y = f2bf(v.y); o.z = f2bf(v.z); o.w = f2bf(v.w);
  } else {
    o = make_ushort4(0, 0, 0, 0);
  }
  *(ushort4*)&xb[elem] = o;
}

__global__ void convw_kernel(const float* __restrict__ w, unsigned short* __restrict__ wb) {
  int i4 = blockIdx.x * 256 + threadIdx.x;
  int elem = i4 * 4;
  const float4 v = *(const float4*)&w[elem];
  ushort4 o;
  o.x = f2bf(v.x); o.y = f2bf(v.y); o.z = f2bf(v.z); o.w = f2bf(v.w);
  *(ushort4*)&wb[elem] = o;
}

// ---------------- bf16 MFMA GEMM: hs = rsqrt(deg) * (x @ W^T) ----------------
// A = xb [npad, 256] bf16 row-major (K-contig), B = wb [256, 256] bf16 row-major
// (K-contig, i.e. already B^T orientation). C = A*B^T pattern, 128x128 block
// tile, 4 waves in 2x2, each wave 64x64 via 4x4 tiles of 16x16x32.
__launch_bounds__(256)
__global__ void gemm_kernel(const unsigned short* __restrict__ A,
                            const unsigned short* __restrict__ B,
                            unsigned short* __restrict__ Hout,
                            const float* __restrict__ rnorm, int n) {
  __shared__ unsigned short sA[128 * 32];
  __shared__ unsigned short sB[128 * 32];
  int tid = threadIdx.x;
  int wave = tid >> 6, lane = tid & 63;
  int wm = wave >> 1, wn = wave & 1;
  int l16 = lane & 15, quad = lane >> 4;
  int arow0 = blockIdx.x * 128;
  int brow0 = blockIdx.y * 128;

  f32x4 acc[4][4];
  const f32x4 zero = {0.f, 0.f, 0.f, 0.f};
#pragma unroll
  for (int i = 0; i < 4; i++)
#pragma unroll
    for (int j = 0; j < 4; j++) acc[i][j] = zero;

  for (int k0 = 0; k0 < 256; k0 += 32) {
#pragma unroll
    for (int it = 0; it < 2; ++it) {
      int c = it * 256 + tid;           // 0..511 chunk of 8 bf16
      int row = c >> 2, cc = (c & 3) * 8;
      *(int4*)&sA[c * 8] = *(const int4*)&A[(arow0 + row) * 256 + k0 + cc];
      *(int4*)&sB[c * 8] = *(const int4*)&B[(brow0 + row) * 256 + k0 + cc];
    }
    __syncthreads();
    short8 af[4], bfr[4];
#pragma unroll
    for (int i = 0; i < 4; i++)
      af[i] = *(const short8*)&sA[(wm * 64 + i * 16 + l16) * 32 + quad * 8];
#pragma unroll
    for (int j = 0; j < 4; j++)
      bfr[j] = *(const short8*)&sB[(wn * 64 + j * 16 + l16) * 32 + quad * 8];
#pragma unroll
    for (int i = 0; i < 4; i++)
#pragma unroll
      for (int j = 0; j < 4; j++)
        acc[i][j] = __builtin_amdgcn_mfma_f32_16x16x32_bf16(af[i], bfr[j], acc[i][j], 0, 0, 0);
    __syncthreads();
  }

  // epilogue: scale row m by rnorm[m], store bf16
#pragma unroll
  for (int i = 0; i < 4; i++) {
    int rowb = arow0 + wm * 64 + i * 16 + quad * 4;
#pragma unroll
    for (int r = 0; r < 4; r++) {
      int gr = rowb + r;
      float rn = (gr < n) ? rnorm[gr] : 0.f;
#pragma unroll
      for (int j = 0; j < 4; j++) {
        int col = brow0 + wn * 64 + j * 16 + l16;
        Hout[gr * 256 + col] = f2bf(acc[i][j][r] * rn);
      }
    }
  }
}

// ---------------- CSR gather: out[i] = rn_i * (hs[i] + sum hs[dst]) ----------------
__launch_bounds__(256)
__global__ void gather_kernel(const unsigned short* __restrict__ hs,
                              const int* __restrict__ offsets,
                              const int* __restrict__ ecount,
                              const float* __restrict__ rnorm,
                              const int* __restrict__ csr,
                              float* __restrict__ out, int n) {
  int wave = threadIdx.x >> 6, lane = threadIdx.x & 63;
  int node = blockIdx.x * 4 + wave;
  if (node >= n) return;
  int start = offsets[node], cnt = ecount[node];
  float a0 = 0.f, a1 = 0.f, a2 = 0.f, a3 = 0.f;
  for (int base = 0; base < cnt; base += 64) {
    int m = cnt - base;
    if (m > 64) m = 64;
    int idxv = 0;
    if (lane < m) idxv = csr[start + base + lane];
    int t = 0;
    for (; t + 4 <= m; t += 4) {
      int d0 = __shfl(idxv, t);
      int d1 = __shfl(idxv, t + 1);
      int d2 = __shfl(idxv, t + 2);
      int d3 = __shfl(idxv, t + 3);
      ushort4 u0 = *(const ushort4*)&hs[d0 * 256 + lane * 4];
      ushort4 u1 = *(const ushort4*)&hs[d1 * 256 + lane * 4];
      ushort4 u2 = *(const ushort4*)&hs[d2 * 256 + lane * 4];
      ushort4 u3 = *(const ushort4*)&hs[d3 * 256 + lane * 4];
      a0 += bf2f(u0.x) + bf2f(u1.x) + bf2f(u2.x) + bf2f(u3.x);
      a1 += bf2f(u0.y) + bf2f(u1.y) + bf2f(u2.y) + bf2f(u3.y);
      a2 += bf2f(u0.z) + bf2f(u1.z) + bf2f(u2.z) + bf2f(u3.z);
      a3 += bf2f(u0.w) + bf2f(u1.w) + bf2f(u2.w) + bf2f(u3.w);
    }
    for (; t < m; ++t) {
      int d = __shfl(idxv, t);
      ushort4 u = *(const ushort4*)&hs[d * 256 + lane * 4];
      a0 += bf2f(u.x); a1 += bf2f(u.y); a2 += bf2f(u.z); a3 += bf2f(u.w);
    }
  }
  ushort4 us = *(const ushort4*)&hs[node * 256 + lane * 4];
  float rn = rnorm[node];
  float4 o;
  o.x = rn * (a0 + bf2f(us.x));
  o.y = rn * (a1 + bf2f(us.y));
  o.z = rn * (a2 + bf2f(us.z));
  o.w = rn * (a3 + bf2f(us.w));
  *(float4*)&out[node * 256 + lane * 4] = o;
}

extern "C" void kernel_launch(void* const* d_in, const int* in_sizes, int n_in,
                              void* d_out, int out_size, void* d_ws, size_t ws_size,
                              hipStream_t stream) {
  const float* x = (const float*)d_in[0];
  const float* W = (const float*)d_in[1];
  const int* ei = (const int*)d_in[2];
  float* out = (float*)d_out;

  int N = in_sizes[0] / D;        // 100000
  int E = in_sizes[2] / 2;        // 3200000
  int NPAD = (N + 127) & ~127;    // 100096
  const int* src = ei;
  const int* dst = ei + E;

  char* p = (char*)d_ws;
  auto alloc = [&](size_t b) {
    char* r = p;
    p += (b + 255) & ~(size_t)255;
    return r;
  };
  unsigned short* xb = (unsigned short*)alloc((size_t)NPAD * D * 2);
  unsigned short* wb = (unsigned short*)alloc((size_t)D * D * 2);
  unsigned short* hb = (unsigned short*)alloc((size_t)NPAD * D * 2);
  int* ecount = (int*)alloc((size_t)N * 4);
  int* offsets = (int*)alloc((size_t)N * 4);
  int* cursor = (int*)alloc((size_t)N * 4);
  int* sums = (int*)alloc(1024 * 4);
  float* rnorm = (float*)alloc((size_t)N * 4);
  int* csr = (int*)alloc((size_t)E * 4);

  hipMemsetAsync(ecount, 0, (size_t)N * 4, stream);
  hist_kernel<<<(E + 255) / 256, 256, 0, stream>>>(src, ecount, E);
  int NB = (N + 1023) / 1024;     // 98 (<=128 required by scan2)
  scan1_kernel<<<NB, 1024, 0, stream>>>(ecount, offsets, sums, N);
  scan2_kernel<<<1, 128, 0, stream>>>(sums, NB);
  scan3_kernel<<<NB, 1024, 0, stream>>>(offsets, sums, cursor, ecount, rnorm, N);
  scatter_kernel<<<(E + 255) / 256, 256, 0, stream>>>(src, dst, cursor, csr, E);
  convx_kernel<<<(NPAD * (D / 4) + 255) / 256, 256, 0, stream>>>(x, xb, N, NPAD);
  convw_kernel<<<(D * D / 4) / 256, 256, 0, stream>>>(W, wb);
  gemm_kernel<<<dim3(NPAD / 128, D / 128), 256, 0, stream>>>(xb, wb, hb, rnorm, N);
  gather_kernel<<<(N + 3) / 4, 256, 0, stream>>>(hb, offsets, ecount, rnorm, csr, out, N);
}

// Round 2
// 539.257 us; speedup vs baseline: 1.5270x; 1.5270x over previous
//
#include <hip/hip_runtime.h>
#include <hip/hip_bf16.h>
#include <stdint.h>

#define D 256
#define NBUCK 391            // ceil(100000 / 256) buckets of 256 nodes
#define BSHIFT 8
#define TILE 4096            // edges per block in binning pass

typedef short short8 __attribute__((ext_vector_type(8)));
typedef float f32x4 __attribute__((ext_vector_type(4)));

__device__ __forceinline__ float bf2f(unsigned short u) {
  return __uint_as_float(((unsigned)u) << 16);
}
__device__ __forceinline__ unsigned short f2bf(float f) {
  unsigned u = __float_as_uint(f);
  unsigned r = u + 0x7FFFu + ((u >> 16) & 1u);
  return (unsigned short)(r >> 16);
}

// ---------------- K1: coarse bucket histogram (LDS-binned) ----------------
__global__ void bucket_hist_kernel(const int* __restrict__ src, int* __restrict__ bcount, int E) {
  __shared__ int h[NBUCK];
  for (int i = threadIdx.x; i < NBUCK; i += 256) h[i] = 0;
  __syncthreads();
  int gid = blockIdx.x * 256 + threadIdx.x;
  for (int e = gid; e < E; e += 256 * 256) atomicAdd(&h[src[e] >> BSHIFT], 1);
  __syncthreads();
  for (int i = threadIdx.x; i < NBUCK; i += 256) {
    int c = h[i];
    if (c) atomicAdd(&bcount[i], c);
  }
}

// ---------------- K2: exclusive scan of bucket counts (1 block, 512 thr) ----------------
__global__ void bucket_scan_kernel(const int* __restrict__ bcount, int* __restrict__ bbase,
                                   int* __restrict__ gcursor) {
  __shared__ int sc[2][512];
  int tid = threadIdx.x;
  sc[0][tid] = (tid < NBUCK) ? bcount[tid] : 0;
  __syncthreads();
  int d = 0;
  for (int off = 1; off < 512; off <<= 1) {
    int v = sc[d][tid];
    if (tid >= off) v += sc[d][tid - off];
    sc[d ^ 1][tid] = v;
    __syncthreads();
    d ^= 1;
  }
  if (tid < NBUCK) {
    int excl = (tid == 0) ? 0 : sc[d][tid - 1];
    bbase[tid] = excl;
    gcursor[tid] = excl;
  }
}

// ---------------- K3: binning scatter — LDS-stage tile sorted by bucket ----------------
// ebuf entry: dst | ((src & 255) << 20)   (dst < 2^20, node_local 8 bits)
__launch_bounds__(256)
__global__ void binscatter_kernel(const int* __restrict__ src, const int* __restrict__ dst,
                                  int* __restrict__ gcursor, int* __restrict__ ebuf, int E) {
  __shared__ int hist[NBUCK];
  __shared__ int lstart[512];
  __shared__ int gbase[NBUCK];
  __shared__ int sc[2][512];
  __shared__ int stag[TILE];
  __shared__ unsigned short sbuck[TILE];

  int tid = threadIdx.x;
  int base = blockIdx.x * TILE;
  int tilecount = E - base;
  if (tilecount > TILE) tilecount = TILE;

  for (int i = tid; i < NBUCK; i += 256) hist[i] = 0;
  __syncthreads();

  int esrc[16], edst[16];
#pragma unroll
  for (int k = 0; k < 16; k++) {
    int e = base + k * 256 + tid;
    if (e < E) {
      esrc[k] = src[e];
      edst[k] = dst[e];
      atomicAdd(&hist[esrc[k] >> BSHIFT], 1);
    } else {
      esrc[k] = -1;
      edst[k] = 0;
    }
  }
  __syncthreads();

  // exclusive scan hist -> lstart (pad to 512, double-buffered Hillis-Steele)
  for (int i = tid; i < 512; i += 256) sc[0][i] = (i < NBUCK) ? hist[i] : 0;
  __syncthreads();
  int d = 0;
  for (int off = 1; off < 512; off <<= 1) {
    for (int i = tid; i < 512; i += 256) {
      int v = sc[d][i];
      if (i >= off) v += sc[d][i - off];
      sc[d ^ 1][i] = v;
    }
    __syncthreads();
    d ^= 1;
  }
  for (int i = tid; i < 512; i += 256) lstart[i] = (i == 0) ? 0 : sc[d][i - 1];
  __syncthreads();

  // reserve global ranges: one atomic per nonempty bucket
  for (int b = tid; b < NBUCK; b += 256) {
    int c = hist[b];
    if (c) gbase[b] = atomicAdd(&gcursor[b], c);
  }
  __syncthreads();

  // reset hist as rank counters
  for (int i = tid; i < NBUCK; i += 256) hist[i] = 0;
  __syncthreads();

  // stage sorted-by-bucket into LDS
#pragma unroll
  for (int k = 0; k < 16; k++) {
    if (esrc[k] >= 0) {
      int b = esrc[k] >> BSHIFT;
      int r = atomicAdd(&hist[b], 1);
      int pos = lstart[b] + r;
      stag[pos] = edst[k] | ((esrc[k] & 255) << 20);
      sbuck[pos] = (unsigned short)b;
    }
  }
  __syncthreads();

  // write out: per-bucket contiguous chunks
  for (int s = tid; s < tilecount; s += 256) {
    int b = sbuck[s];
    ebuf[gbase[b] + (s - lstart[b])] = stag[s];
  }
}

// ---------------- K4: per-bucket counting sort -> csr, offsets, counts, rnorm ----------------
__launch_bounds__(256)
__global__ void bucketsort_kernel(const int* __restrict__ ebuf, const int* __restrict__ bbase,
                                  const int* __restrict__ bcount, int* __restrict__ csr,
                                  int* __restrict__ offsets, int* __restrict__ ecount,
                                  float* __restrict__ rnorm, int N) {
  __shared__ int ncnt[256];
  __shared__ int nstart[256];
  __shared__ int sc[2][256];
  int tid = threadIdx.x;
  int b = blockIdx.x;
  int base = bbase[b];
  int cnt = bcount[b];
  int node0 = b << BSHIFT;

  ncnt[tid] = 0;
  __syncthreads();
  for (int s = tid; s < cnt; s += 256) {
    int v = ebuf[base + s];
    atomicAdd(&ncnt[v >> 20], 1);
  }
  __syncthreads();

  int mycnt = ncnt[tid];
  // exclusive scan over 256
  sc[0][tid] = mycnt;
  __syncthreads();
  int d = 0;
  for (int off = 1; off < 256; off <<= 1) {
    int v = sc[d][tid];
    if (tid >= off) v += sc[d][tid - off];
    sc[d ^ 1][tid] = v;
    __syncthreads();
    d ^= 1;
  }
  nstart[tid] = (tid == 0) ? 0 : sc[d][tid - 1];
  __syncthreads();

  int node = node0 + tid;
  if (node < N) {
    offsets[node] = base + nstart[tid];
    ecount[node] = mycnt;
    rnorm[node] = rsqrtf((float)(mycnt + 1));
  }

  ncnt[tid] = 0;
  __syncthreads();
  for (int s = tid; s < cnt; s += 256) {
    int v = ebuf[base + s];
    int nl = v >> 20;
    int r = atomicAdd(&ncnt[nl], 1);
    csr[base + nstart[nl] + r] = v & 0xFFFFF;
  }
}

// ---------------- fp32 -> bf16 conversions ----------------
__global__ void convx_kernel(const float* __restrict__ x, unsigned short* __restrict__ xb,
                             int n, int npad) {
  int i4 = blockIdx.x * 256 + threadIdx.x;
  long long elem = (long long)i4 * 4;
  if (elem >= (long long)npad * D) return;
  int row = (int)(elem / D);
  ushort4 o;
  if (row < n) {
    const float4 v = *(const float4*)&x[elem];
    o.x = f2bf(v.x); o.y = f2bf(v.y); o.z = f2bf(v.z); o.w = f2bf(v.w);
  } else {
    o = make_ushort4(0, 0, 0, 0);
  }
  *(ushort4*)&xb[elem] = o;
}

__global__ void convw_kernel(const float* __restrict__ w, unsigned short* __restrict__ wb) {
  int i4 = blockIdx.x * 256 + threadIdx.x;
  int elem = i4 * 4;
  const float4 v = *(const float4*)&w[elem];
  ushort4 o;
  o.x = f2bf(v.x); o.y = f2bf(v.y); o.z = f2bf(v.z); o.w = f2bf(v.w);
  *(ushort4*)&wb[elem] = o;
}

// ---------------- bf16 MFMA GEMM: hs = rsqrt(deg) * (x @ W^T) ----------------
__launch_bounds__(256)
__global__ void gemm_kernel(const unsigned short* __restrict__ A,
                            const unsigned short* __restrict__ B,
                            unsigned short* __restrict__ Hout,
                            const float* __restrict__ rnorm, int n) {
  __shared__ unsigned short sA[128 * 32];
  __shared__ unsigned short sB[128 * 32];
  int tid = threadIdx.x;
  int wave = tid >> 6, lane = tid & 63;
  int wm = wave >> 1, wn = wave & 1;
  int l16 = lane & 15, quad = lane >> 4;
  int arow0 = blockIdx.x * 128;
  int brow0 = blockIdx.y * 128;

  f32x4 acc[4][4];
  const f32x4 zero = {0.f, 0.f, 0.f, 0.f};
#pragma unroll
  for (int i = 0; i < 4; i++)
#pragma unroll
    for (int j = 0; j < 4; j++) acc[i][j] = zero;

  for (int k0 = 0; k0 < 256; k0 += 32) {
#pragma unroll
    for (int it = 0; it < 2; ++it) {
      int c = it * 256 + tid;
      int row = c >> 2, cc = (c & 3) * 8;
      *(int4*)&sA[c * 8] = *(const int4*)&A[(arow0 + row) * 256 + k0 + cc];
      *(int4*)&sB[c * 8] = *(const int4*)&B[(brow0 + row) * 256 + k0 + cc];
    }
    __syncthreads();
    short8 af[4], bfr[4];
#pragma unroll
    for (int i = 0; i < 4; i++)
      af[i] = *(const short8*)&sA[(wm * 64 + i * 16 + l16) * 32 + quad * 8];
#pragma unroll
    for (int j = 0; j < 4; j++)
      bfr[j] = *(const short8*)&sB[(wn * 64 + j * 16 + l16) * 32 + quad * 8];
#pragma unroll
    for (int i = 0; i < 4; i++)
#pragma unroll
      for (int j = 0; j < 4; j++)
        acc[i][j] = __builtin_amdgcn_mfma_f32_16x16x32_bf16(af[i], bfr[j], acc[i][j], 0, 0, 0);
    __syncthreads();
  }

#pragma unroll
  for (int i = 0; i < 4; i++) {
    int rowb = arow0 + wm * 64 + i * 16 + quad * 4;
#pragma unroll
    for (int r = 0; r < 4; r++) {
      int gr = rowb + r;
      float rn = (gr < n) ? rnorm[gr] : 0.f;
#pragma unroll
      for (int j = 0; j < 4; j++) {
        int col = brow0 + wn * 64 + j * 16 + l16;
        Hout[gr * 256 + col] = f2bf(acc[i][j][r] * rn);
      }
    }
  }
}

// ---------------- CSR gather: out[i] = rn_i * (hs[i] + sum hs[dst]) ----------------
__launch_bounds__(256)
__global__ void gather_kernel(const unsigned short* __restrict__ hs,
                              const int* __restrict__ offsets,
                              const int* __restrict__ ecount,
                              const float* __restrict__ rnorm,
                              const int* __restrict__ csr,
                              float* __restrict__ out, int n) {
  int wave = threadIdx.x >> 6, lane = threadIdx.x & 63;
  int node = blockIdx.x * 4 + wave;
  if (node >= n) return;
  int start = offsets[node], cnt = ecount[node];
  float a0 = 0.f, a1 = 0.f, a2 = 0.f, a3 = 0.f;
  for (int base = 0; base < cnt; base += 64) {
    int m = cnt - base;
    if (m > 64) m = 64;
    int idxv = 0;
    if (lane < m) idxv = csr[start + base + lane];
    int t = 0;
    for (; t + 4 <= m; t += 4) {
      int d0 = __shfl(idxv, t);
      int d1 = __shfl(idxv, t + 1);
      int d2 = __shfl(idxv, t + 2);
      int d3 = __shfl(idxv, t + 3);
      ushort4 u0 = *(const ushort4*)&hs[d0 * 256 + lane * 4];
      ushort4 u1 = *(const ushort4*)&hs[d1 * 256 + lane * 4];
      ushort4 u2 = *(const ushort4*)&hs[d2 * 256 + lane * 4];
      ushort4 u3 = *(const ushort4*)&hs[d3 * 256 + lane * 4];
      a0 += bf2f(u0.x) + bf2f(u1.x) + bf2f(u2.x) + bf2f(u3.x);
      a1 += bf2f(u0.y) + bf2f(u1.y) + bf2f(u2.y) + bf2f(u3.y);
      a2 += bf2f(u0.z) + bf2f(u1.z) + bf2f(u2.z) + bf2f(u3.z);
      a3 += bf2f(u0.w) + bf2f(u1.w) + bf2f(u2.w) + bf2f(u3.w);
    }
    for (; t < m; ++t) {
      int dd = __shfl(idxv, t);
      ushort4 u = *(const ushort4*)&hs[dd * 256 + lane * 4];
      a0 += bf2f(u.x); a1 += bf2f(u.y); a2 += bf2f(u.z); a3 += bf2f(u.w);
    }
  }
  ushort4 us = *(const ushort4*)&hs[node * 256 + lane * 4];
  float rn = rnorm[node];
  float4 o;
  o.x = rn * (a0 + bf2f(us.x));
  o.y = rn * (a1 + bf2f(us.y));
  o.z = rn * (a2 + bf2f(us.z));
  o.w = rn * (a3 + bf2f(us.w));
  *(float4*)&out[node * 256 + lane * 4] = o;
}

extern "C" void kernel_launch(void* const* d_in, const int* in_sizes, int n_in,
                              void* d_out, int out_size, void* d_ws, size_t ws_size,
                              hipStream_t stream) {
  const float* x = (const float*)d_in[0];
  const float* W = (const float*)d_in[1];
  const int* ei = (const int*)d_in[2];
  float* out = (float*)d_out;

  int N = in_sizes[0] / D;        // 100000
  int E = in_sizes[2] / 2;        // 3200000
  int NPAD = (N + 127) & ~127;
  const int* src = ei;
  const int* dst = ei + E;

  char* p = (char*)d_ws;
  auto alloc = [&](size_t b) {
    char* r = p;
    p += (b + 255) & ~(size_t)255;
    return r;
  };
  unsigned short* xb = (unsigned short*)alloc((size_t)NPAD * D * 2);
  unsigned short* wb = (unsigned short*)alloc((size_t)D * D * 2);
  unsigned short* hb = (unsigned short*)alloc((size_t)NPAD * D * 2);
  int* csr = (int*)alloc((size_t)E * 4);
  int* offsets = (int*)alloc((size_t)N * 4);
  int* ecount = (int*)alloc((size_t)N * 4);
  float* rnorm = (float*)alloc((size_t)N * 4);
  int* bcount = (int*)alloc(NBUCK * 4);
  int* bbase = (int*)alloc(NBUCK * 4);
  int* gcursor = (int*)alloc(NBUCK * 4);
  // ebuf (E*4 = 12.8 MB) aliases hb (51 MB): dead before gemm writes hb
  int* ebuf = (int*)hb;

  hipMemsetAsync(bcount, 0, NBUCK * 4, stream);
  bucket_hist_kernel<<<256, 256, 0, stream>>>(src, bcount, E);
  bucket_scan_kernel<<<1, 512, 0, stream>>>(bcount, bbase, gcursor);
  binscatter_kernel<<<(E + TILE - 1) / TILE, 256, 0, stream>>>(src, dst, gcursor, ebuf, E);
  bucketsort_kernel<<<NBUCK, 256, 0, stream>>>(ebuf, bbase, bcount, csr, offsets, ecount, rnorm, N);
  convx_kernel<<<(NPAD * (D / 4) + 255) / 256, 256, 0, stream>>>(x, xb, N, NPAD);
  convw_kernel<<<(D * D / 4) / 256, 256, 0, stream>>>(W, wb);
  gemm_kernel<<<dim3(NPAD / 128, D / 128), 256, 0, stream>>>(xb, wb, hb, rnorm, N);
  gather_kernel<<<(N + 3) / 4, 256, 0, stream>>>(hb, offsets, ecount, rnorm, csr, out, N);
}

// Round 3
// 528.225 us; speedup vs baseline: 1.5589x; 1.0209x over previous
//
#include <hip/hip_runtime.h>
#include <hip/hip_bf16.h>
#include <stdint.h>

#define D 256
#define NBUCK 391            // ceil(100000 / 256) buckets of 256 nodes
#define BSHIFT 8
#define TILE 4096            // edges per block in binning pass

typedef short short8 __attribute__((ext_vector_type(8)));
typedef float f32x4 __attribute__((ext_vector_type(4)));

__device__ __forceinline__ float bf2f(unsigned short u) {
  return __uint_as_float(((unsigned)u) << 16);
}
__device__ __forceinline__ unsigned short f2bf(float f) {
  unsigned u = __float_as_uint(f);
  unsigned r = u + 0x7FFFu + ((u >> 16) & 1u);
  return (unsigned short)(r >> 16);
}

// ---------------- K1: coarse bucket histogram (LDS-binned) ----------------
__global__ void bucket_hist_kernel(const int* __restrict__ src, int* __restrict__ bcount, int E) {
  __shared__ int h[NBUCK];
  for (int i = threadIdx.x; i < NBUCK; i += 256) h[i] = 0;
  __syncthreads();
  int gid = blockIdx.x * 256 + threadIdx.x;
  for (int e = gid; e < E; e += 256 * 256) atomicAdd(&h[src[e] >> BSHIFT], 1);
  __syncthreads();
  for (int i = threadIdx.x; i < NBUCK; i += 256) {
    int c = h[i];
    if (c) atomicAdd(&bcount[i], c);
  }
}

// ---------------- K2: exclusive scan of bucket counts ----------------
__global__ void bucket_scan_kernel(const int* __restrict__ bcount, int* __restrict__ bbase,
                                   int* __restrict__ gcursor) {
  __shared__ int sc[2][512];
  int tid = threadIdx.x;
  sc[0][tid] = (tid < NBUCK) ? bcount[tid] : 0;
  __syncthreads();
  int d = 0;
  for (int off = 1; off < 512; off <<= 1) {
    int v = sc[d][tid];
    if (tid >= off) v += sc[d][tid - off];
    sc[d ^ 1][tid] = v;
    __syncthreads();
    d ^= 1;
  }
  if (tid < NBUCK) {
    int excl = (tid == 0) ? 0 : sc[d][tid - 1];
    bbase[tid] = excl;
    gcursor[tid] = excl;
  }
}

// ---------------- K3: binning scatter ----------------
__launch_bounds__(256)
__global__ void binscatter_kernel(const int* __restrict__ src, const int* __restrict__ dst,
                                  int* __restrict__ gcursor, int* __restrict__ ebuf, int E) {
  __shared__ int hist[NBUCK];
  __shared__ int lstart[512];
  __shared__ int gbase[NBUCK];
  __shared__ int sc[2][512];
  __shared__ int stag[TILE];
  __shared__ unsigned short sbuck[TILE];

  int tid = threadIdx.x;
  int base = blockIdx.x * TILE;
  int tilecount = E - base;
  if (tilecount > TILE) tilecount = TILE;

  for (int i = tid; i < NBUCK; i += 256) hist[i] = 0;
  __syncthreads();

  int esrc[16], edst[16];
#pragma unroll
  for (int k = 0; k < 16; k++) {
    int e = base + k * 256 + tid;
    if (e < E) {
      esrc[k] = src[e];
      edst[k] = dst[e];
      atomicAdd(&hist[esrc[k] >> BSHIFT], 1);
    } else {
      esrc[k] = -1;
      edst[k] = 0;
    }
  }
  __syncthreads();

  for (int i = tid; i < 512; i += 256) sc[0][i] = (i < NBUCK) ? hist[i] : 0;
  __syncthreads();
  int d = 0;
  for (int off = 1; off < 512; off <<= 1) {
    for (int i = tid; i < 512; i += 256) {
      int v = sc[d][i];
      if (i >= off) v += sc[d][i - off];
      sc[d ^ 1][i] = v;
    }
    __syncthreads();
    d ^= 1;
  }
  for (int i = tid; i < 512; i += 256) lstart[i] = (i == 0) ? 0 : sc[d][i - 1];
  __syncthreads();

  for (int b = tid; b < NBUCK; b += 256) {
    int c = hist[b];
    if (c) gbase[b] = atomicAdd(&gcursor[b], c);
  }
  __syncthreads();

  for (int i = tid; i < NBUCK; i += 256) hist[i] = 0;
  __syncthreads();

#pragma unroll
  for (int k = 0; k < 16; k++) {
    if (esrc[k] >= 0) {
      int b = esrc[k] >> BSHIFT;
      int r = atomicAdd(&hist[b], 1);
      int pos = lstart[b] + r;
      stag[pos] = edst[k] | ((esrc[k] & 255) << 20);
      sbuck[pos] = (unsigned short)b;
    }
  }
  __syncthreads();

  for (int s = tid; s < tilecount; s += 256) {
    int b = sbuck[s];
    ebuf[gbase[b] + (s - lstart[b])] = stag[s];
  }
}

// ---------------- K4: per-bucket counting sort ----------------
__launch_bounds__(256)
__global__ void bucketsort_kernel(const int* __restrict__ ebuf, const int* __restrict__ bbase,
                                  const int* __restrict__ bcount, int* __restrict__ csr,
                                  int* __restrict__ offsets, int* __restrict__ ecount,
                                  float* __restrict__ rnorm, int N) {
  __shared__ int ncnt[256];
  __shared__ int nstart[256];
  __shared__ int sc[2][256];
  int tid = threadIdx.x;
  int b = blockIdx.x;
  int base = bbase[b];
  int cnt = bcount[b];
  int node0 = b << BSHIFT;

  ncnt[tid] = 0;
  __syncthreads();
  for (int s = tid; s < cnt; s += 256) {
    int v = ebuf[base + s];
    atomicAdd(&ncnt[v >> 20], 1);
  }
  __syncthreads();

  int mycnt = ncnt[tid];
  sc[0][tid] = mycnt;
  __syncthreads();
  int d = 0;
  for (int off = 1; off < 256; off <<= 1) {
    int v = sc[d][tid];
    if (tid >= off) v += sc[d][tid - off];
    sc[d ^ 1][tid] = v;
    __syncthreads();
    d ^= 1;
  }
  nstart[tid] = (tid == 0) ? 0 : sc[d][tid - 1];
  __syncthreads();

  int node = node0 + tid;
  if (node < N) {
    offsets[node] = base + nstart[tid];
    ecount[node] = mycnt;
    rnorm[node] = rsqrtf((float)(mycnt + 1));
  }

  ncnt[tid] = 0;
  __syncthreads();
  for (int s = tid; s < cnt; s += 256) {
    int v = ebuf[base + s];
    int nl = v >> 20;
    int r = atomicAdd(&ncnt[nl], 1);
    csr[base + nstart[nl] + r] = v & 0xFFFFF;
  }
}

// ---------------- fp32 -> bf16 conversions ----------------
__global__ void convx_kernel(const float* __restrict__ x, unsigned short* __restrict__ xb,
                             int n, int npad) {
  int i4 = blockIdx.x * 256 + threadIdx.x;
  long long elem = (long long)i4 * 4;
  if (elem >= (long long)npad * D) return;
  int row = (int)(elem / D);
  ushort4 o;
  if (row < n) {
    const float4 v = *(const float4*)&x[elem];
    o.x = f2bf(v.x); o.y = f2bf(v.y); o.z = f2bf(v.z); o.w = f2bf(v.w);
  } else {
    o = make_ushort4(0, 0, 0, 0);
  }
  *(ushort4*)&xb[elem] = o;
}

__global__ void convw_kernel(const float* __restrict__ w, unsigned short* __restrict__ wb) {
  int i4 = blockIdx.x * 256 + threadIdx.x;
  int elem = i4 * 4;
  const float4 v = *(const float4*)&w[elem];
  ushort4 o;
  o.x = f2bf(v.x); o.y = f2bf(v.y); o.z = f2bf(v.z); o.w = f2bf(v.w);
  *(ushort4*)&wb[elem] = o;
}

// ---------------- bf16 MFMA GEMM: hs = rsqrt(deg) * (x @ W^T) ----------------
__launch_bounds__(256)
__global__ void gemm_kernel(const unsigned short* __restrict__ A,
                            const unsigned short* __restrict__ B,
                            unsigned short* __restrict__ Hout,
                            const float* __restrict__ rnorm, int n) {
  __shared__ unsigned short sA[128 * 32];
  __shared__ unsigned short sB[128 * 32];
  int tid = threadIdx.x;
  int wave = tid >> 6, lane = tid & 63;
  int wm = wave >> 1, wn = wave & 1;
  int l16 = lane & 15, quad = lane >> 4;
  int arow0 = blockIdx.x * 128;
  int brow0 = blockIdx.y * 128;

  f32x4 acc[4][4];
  const f32x4 zero = {0.f, 0.f, 0.f, 0.f};
#pragma unroll
  for (int i = 0; i < 4; i++)
#pragma unroll
    for (int j = 0; j < 4; j++) acc[i][j] = zero;

  for (int k0 = 0; k0 < 256; k0 += 32) {
#pragma unroll
    for (int it = 0; it < 2; ++it) {
      int c = it * 256 + tid;
      int row = c >> 2, cc = (c & 3) * 8;
      *(int4*)&sA[c * 8] = *(const int4*)&A[(arow0 + row) * 256 + k0 + cc];
      *(int4*)&sB[c * 8] = *(const int4*)&B[(brow0 + row) * 256 + k0 + cc];
    }
    __syncthreads();
    short8 af[4], bfr[4];
#pragma unroll
    for (int i = 0; i < 4; i++)
      af[i] = *(const short8*)&sA[(wm * 64 + i * 16 + l16) * 32 + quad * 8];
#pragma unroll
    for (int j = 0; j < 4; j++)
      bfr[j] = *(const short8*)&sB[(wn * 64 + j * 16 + l16) * 32 + quad * 8];
#pragma unroll
    for (int i = 0; i < 4; i++)
#pragma unroll
      for (int j = 0; j < 4; j++)
        acc[i][j] = __builtin_amdgcn_mfma_f32_16x16x32_bf16(af[i], bfr[j], acc[i][j], 0, 0, 0);
    __syncthreads();
  }

#pragma unroll
  for (int i = 0; i < 4; i++) {
    int rowb = arow0 + wm * 64 + i * 16 + quad * 4;
#pragma unroll
    for (int r = 0; r < 4; r++) {
      int gr = rowb + r;
      float rn = (gr < n) ? rnorm[gr] : 0.f;
#pragma unroll
      for (int j = 0; j < 4; j++) {
        int col = brow0 + wn * 64 + j * 16 + l16;
        Hout[gr * 256 + col] = f2bf(acc[i][j][r] * rn);
      }
    }
  }
}

// ---------------- CSR gather, column-split pass ----------------
// Pass handles cols [colbase, colbase+128). Lane owns 2 cols (4 B/edge load).
// out[node][c] = rn * (hs[node][c] + sum_dst hs[dst][c])
__launch_bounds__(256)
__global__ void gather_kernel(const unsigned short* __restrict__ hs,
                              const int* __restrict__ offsets,
                              const int* __restrict__ ecount,
                              const float* __restrict__ rnorm,
                              const int* __restrict__ csr,
                              float* __restrict__ out, int n, int colbase) {
  int wave = threadIdx.x >> 6, lane = threadIdx.x & 63;
  int node = blockIdx.x * 4 + wave;
  if (node >= n) return;
  int start = offsets[node], cnt = ecount[node];
  const unsigned short* hcol = hs + colbase + lane * 2;
  float a0 = 0.f, a1 = 0.f;
  for (int base = 0; base < cnt; base += 64) {
    int m = cnt - base;
    if (m > 64) m = 64;
    int idxv = 0;
    if (lane < m) idxv = csr[start + base + lane];
    int t = 0;
    for (; t + 8 <= m; t += 8) {
      int d0 = __shfl(idxv, t);
      int d1 = __shfl(idxv, t + 1);
      int d2 = __shfl(idxv, t + 2);
      int d3 = __shfl(idxv, t + 3);
      int d4 = __shfl(idxv, t + 4);
      int d5 = __shfl(idxv, t + 5);
      int d6 = __shfl(idxv, t + 6);
      int d7 = __shfl(idxv, t + 7);
      unsigned u0 = *(const unsigned*)&hcol[d0 * 256];
      unsigned u1 = *(const unsigned*)&hcol[d1 * 256];
      unsigned u2 = *(const unsigned*)&hcol[d2 * 256];
      unsigned u3 = *(const unsigned*)&hcol[d3 * 256];
      unsigned u4 = *(const unsigned*)&hcol[d4 * 256];
      unsigned u5 = *(const unsigned*)&hcol[d5 * 256];
      unsigned u6 = *(const unsigned*)&hcol[d6 * 256];
      unsigned u7 = *(const unsigned*)&hcol[d7 * 256];
      a0 += bf2f((unsigned short)u0) + bf2f((unsigned short)u1) +
            bf2f((unsigned short)u2) + bf2f((unsigned short)u3) +
            bf2f((unsigned short)u4) + bf2f((unsigned short)u5) +
            bf2f((unsigned short)u6) + bf2f((unsigned short)u7);
      a1 += bf2f((unsigned short)(u0 >> 16)) + bf2f((unsigned short)(u1 >> 16)) +
            bf2f((unsigned short)(u2 >> 16)) + bf2f((unsigned short)(u3 >> 16)) +
            bf2f((unsigned short)(u4 >> 16)) + bf2f((unsigned short)(u5 >> 16)) +
            bf2f((unsigned short)(u6 >> 16)) + bf2f((unsigned short)(u7 >> 16));
    }
    for (; t < m; ++t) {
      int dd = __shfl(idxv, t);
      unsigned u = *(const unsigned*)&hcol[dd * 256];
      a0 += bf2f((unsigned short)u);
      a1 += bf2f((unsigned short)(u >> 16));
    }
  }
  unsigned us = *(const unsigned*)&hcol[node * 256];
  float rn = rnorm[node];
  float2 o;
  o.x = rn * (a0 + bf2f((unsigned short)us));
  o.y = rn * (a1 + bf2f((unsigned short)(us >> 16)));
  *(float2*)&out[node * 256 + colbase + lane * 2] = o;
}

extern "C" void kernel_launch(void* const* d_in, const int* in_sizes, int n_in,
                              void* d_out, int out_size, void* d_ws, size_t ws_size,
                              hipStream_t stream) {
  const float* x = (const float*)d_in[0];
  const float* W = (const float*)d_in[1];
  const int* ei = (const int*)d_in[2];
  float* out = (float*)d_out;

  int N = in_sizes[0] / D;        // 100000
  int E = in_sizes[2] / 2;        // 3200000
  int NPAD = (N + 127) & ~127;
  const int* src = ei;
  const int* dst = ei + E;

  char* p = (char*)d_ws;
  auto alloc = [&](size_t b) {
    char* r = p;
    p += (b + 255) & ~(size_t)255;
    return r;
  };
  unsigned short* xb = (unsigned short*)alloc((size_t)NPAD * D * 2);
  unsigned short* wb = (unsigned short*)alloc((size_t)D * D * 2);
  unsigned short* hb = (unsigned short*)alloc((size_t)NPAD * D * 2);
  int* csr = (int*)alloc((size_t)E * 4);
  int* offsets = (int*)alloc((size_t)N * 4);
  int* ecount = (int*)alloc((size_t)N * 4);
  float* rnorm = (float*)alloc((size_t)N * 4);
  int* bcount = (int*)alloc(NBUCK * 4);
  int* bbase = (int*)alloc(NBUCK * 4);
  int* gcursor = (int*)alloc(NBUCK * 4);
  // ebuf (E*4 = 12.8 MB) aliases hb (51 MB): dead before gemm writes hb
  int* ebuf = (int*)hb;

  hipMemsetAsync(bcount, 0, NBUCK * 4, stream);
  bucket_hist_kernel<<<256, 256, 0, stream>>>(src, bcount, E);
  bucket_scan_kernel<<<1, 512, 0, stream>>>(bcount, bbase, gcursor);
  binscatter_kernel<<<(E + TILE - 1) / TILE, 256, 0, stream>>>(src, dst, gcursor, ebuf, E);
  bucketsort_kernel<<<NBUCK, 256, 0, stream>>>(ebuf, bbase, bcount, csr, offsets, ecount, rnorm, N);
  convx_kernel<<<(NPAD * (D / 4) + 255) / 256, 256, 0, stream>>>(x, xb, N, NPAD);
  convw_kernel<<<(D * D / 4) / 256, 256, 0, stream>>>(W, wb);
  gemm_kernel<<<dim3(NPAD / 128, D / 128), 256, 0, stream>>>(xb, wb, hb, rnorm, N);
  gather_kernel<<<(N + 3) / 4, 256, 0, stream>>>(hb, offsets, ecount, rnorm, csr, out, N, 0);
  gather_kernel<<<(N + 3) / 4, 256, 0, stream>>>(hb, offsets, ecount, rnorm, csr, out, N, 128);
}